// Round 1
// baseline (2427.903 us; speedup 1.0000x reference)
//
#include <hip/hip_runtime.h>
#include <math.h>

#define SCALE 0.17677669529663687f

// workspace float offsets
#define OFF_FRW  0l
#define OFF_FTW  33554432l
#define OFF_RRW  67108864l
#define OFF_RTW  67239936l
#define OFF_G    67371008l
#define OFF_Z    71565312l
#define OFF_ZP   73662464l
#define OFF_ZP2  75759616l
#define OFF_QT   77856768l
#define OFF_KT   77922304l
#define OFF_VT   77987840l
#define OFF_F1T  78053376l
#define OFF_PHIT 78315520l
#define OFF_PHB  78446592l
#define OFF_GAM  78446848l

__device__ __forceinline__ float wsum64(float v){
  #pragma unroll
  for(int o=32;o>0;o>>=1) v+=__shfl_xor(v,o,64);
  return v;
}
__device__ __forceinline__ float wmax64(float v){
  #pragma unroll
  for(int o=32;o>0;o>>=1) v=fmaxf(v,__shfl_xor(v,o,64));
  return v;
}
__device__ __forceinline__ float blockSum256(float v, float* red, int t){
  v=wsum64(v);
  __syncthreads();
  if((t&63)==0) red[t>>6]=v;
  __syncthreads();
  return red[0]+red[1]+red[2]+red[3];
}

// ---------------- weight prep: transposes + phi fold ----------------
__global__ __launch_bounds__(256) void k_prep(const float* __restrict__ qw, const float* __restrict__ kw,
                       const float* __restrict__ vw, const float* __restrict__ fc1w,
                       const float* __restrict__ phiw, const float* __restrict__ phibv,
                       float* __restrict__ ws){
  long gid = (long)blockIdx.x*256 + threadIdx.x;
  if(gid < 262144){ long o=gid>>8, i=gid&255; ws[OFF_F1T+gid] = fc1w[i*1024+o]; return; }
  gid -= 262144;
  if(gid < 65536){ long o=gid>>8, i=gid&255; ws[OFF_QT+gid] = qw[i*256+o]; return; }
  gid -= 65536;
  if(gid < 65536){ long o=gid>>8, i=gid&255; ws[OFF_KT+gid] = kw[i*256+o]; return; }
  gid -= 65536;
  if(gid < 65536){ long o=gid>>8, i=gid&255; ws[OFF_VT+gid] = vw[i*256+o]; return; }
  gid -= 65536;
  if(gid < 131072){ long c=gid>>9, k=gid&511; ws[OFF_PHIT+gid] = 0.5f*(phiw[k*512+c] + phiw[k*512+c+256]); return; }
  gid -= 131072;
  if(gid < 256){ ws[OFF_PHB+gid] = 0.5f*(phibv[gid] + phibv[gid+256]); }
}

// ---------------- gamma ----------------
__global__ __launch_bounds__(256) void k_gamma(const float* __restrict__ rR, const float* __restrict__ rT,
                        const float* __restrict__ g1w, const float* __restrict__ g1b,
                        const float* __restrict__ g2w, const float* __restrict__ g2b,
                        float* __restrict__ ws){
  int b=blockIdx.x, t=threadIdx.x;
  const float* pR=rR+(long)b*16384;
  const float* pT=rT+(long)b*16384;
  float sR=0.f, sT=0.f;
  for(int i=t;i<16384;i+=256){ sR+=pR[i]; sT+=pT[i]; }
  __shared__ float red[8];
  sR=wsum64(sR); sT=wsum64(sT);
  if((t&63)==0){ red[t>>6]=sR; red[4+(t>>6)]=sT; }
  __syncthreads();
  if(t==0){
    float mR=(red[0]+red[1]+red[2]+red[3])*(1.f/16384.f);
    float mT=(red[4]+red[5]+red[6]+red[7])*(1.f/16384.f);
    float o=g2b[0];
    for(int j=0;j<8;j++){
      float h=mR*g1w[j]+mT*g1w[8+j]+g1b[j];
      h=fmaxf(h,0.f);
      o+=h*g2w[j];
    }
    ws[OFF_GAM+b]=1.f/(1.f+expf(-o));
  }
}

// ---------------- window partition transpose ----------------
#define TSTRI 129
#define TSTRC 1033
__global__ __launch_bounds__(256) void k_win(const float* __restrict__ FR, const float* __restrict__ FT,
                      const float* __restrict__ rR, const float* __restrict__ rT,
                      float* __restrict__ ws){
  __shared__ float tile[32*TSTRC];
  int cchunk=blockIdx.x, wr=blockIdx.y, b=blockIdx.z, t=threadIdx.x;
  for(int s=0;s<2;s++){
    const float* src = s? FT:FR;
    float* dst = ws + (s? OFF_FTW:OFF_FRW);
    __syncthreads();
    for(int r4=t; r4<8192; r4+=256){
      int row=r4>>5, wq=r4&31;
      int ci=row>>3, i=row&7;
      long saddr = (((long)b*256 + cchunk*32+ci)*128 + wr*8+i)*128 + wq*4;
      float4 v=*(const float4*)(src+saddr);
      float* p=&tile[ci*TSTRC + i*TSTRI + wq*4];
      p[0]=v.x; p[1]=v.y; p[2]=v.z; p[3]=v.w;
    }
    __syncthreads();
    int cl=t&31, tg=t>>5;
    for(int tok=tg; tok<1024; tok+=8){
      int wc=tok>>6, n=tok&63, i=n>>3, j=n&7;
      float v = tile[cl*TSTRC + i*TSTRI + wc*8+j];
      long w = ((long)b*16+wr)*16+wc;
      dst[(w*64+n)*256 + cchunk*32 + cl] = v;
    }
  }
  if(cchunk==0){
    for(int q=0;q<2;q++){
      const float* src=q? rT:rR;
      float* dst=ws + (q? OFF_RTW:OFF_RRW);
      for(int tok=t; tok<1024; tok+=256){
        int wc=tok>>6, n=tok&63, i=n>>3, j=n&7;
        long w=((long)b*16+wr)*16+wc;
        dst[w*64+n] = src[((long)b*128 + wr*8+i)*128 + wc*8+j];
      }
    }
  }
}

// ---------------- stage1: LN(concat) + psi softmax + pooled G ----------------
#define FS 516
__global__ __launch_bounds__(512) void k_stage1(const float* __restrict__ psiw, const float* __restrict__ psib,
                         const float* __restrict__ npg, const float* __restrict__ npb,
                         float* __restrict__ ws){
  __shared__ float F[64*FS];
  __shared__ float psiT[2048];
  __shared__ float ng[512], nb[512];
  __shared__ float mu[64], rsd[64];
  __shared__ float Sp[2048];
  __shared__ float Sa[256];
  int w=blockIdx.x, t=threadIdx.x;
  const float* FRw = ws+OFF_FRW + (long)w*16384;
  const float* FTw = ws+OFF_FTW + (long)w*16384;
  for(int i4=t;i4<8192;i4+=512){
    int n=i4>>7, cq=i4&127; int c=cq*4;
    float4 v = (c<256)? *(const float4*)(FRw + n*256+c) : *(const float4*)(FTw + n*256+c-256);
    float* p=&F[n*FS+c]; p[0]=v.x; p[1]=v.y; p[2]=v.z; p[3]=v.w;
  }
  ng[t&511]=npg[t&511]; nb[t&511]=npb[t&511];
  for(int i=t;i<2048;i+=512){ int c=i>>2, m=i&3; psiT[m*512+c]=psiw[i]; }
  __syncthreads();
  { int g=t>>6, l=t&63;
    for(int n=g;n<64;n+=8){
      float s1=0.f,s2=0.f;
      #pragma unroll
      for(int k=0;k<8;k++){ float x=F[n*FS + l + 64*k]; s1+=x; s2+=x*x; }
      s1=wsum64(s1); s2=wsum64(s2);
      if(l==0){ float mm=s1*(1.f/512.f), vv=s2*(1.f/512.f)-mm*mm; mu[n]=mm; rsd[n]=rsqrtf(vv+1e-5f); }
    } }
  __syncthreads();
  for(int i=t;i<32768;i+=512){ int n=i>>9, c=i&511; F[n*FS+c] = (F[n*FS+c]-mu[n])*rsd[n]*ng[c]+nb[c]; }
  __syncthreads();
  { int n=t&63, sl=t>>6; int c0=sl*64;
    float a0=0.f,a1=0.f,a2=0.f,a3=0.f;
    for(int k=0;k<64;k+=4){
      int c=c0+k;
      float4 f=*(const float4*)&F[n*FS+c];
      float4 p0=*(const float4*)&psiT[c];
      float4 p1=*(const float4*)&psiT[512+c];
      float4 p2=*(const float4*)&psiT[1024+c];
      float4 p3=*(const float4*)&psiT[1536+c];
      a0+=f.x*p0.x+f.y*p0.y+f.z*p0.z+f.w*p0.w;
      a1+=f.x*p1.x+f.y*p1.y+f.z*p1.z+f.w*p1.w;
      a2+=f.x*p2.x+f.y*p2.y+f.z*p2.z+f.w*p2.w;
      a3+=f.x*p3.x+f.y*p3.y+f.z*p3.z+f.w*p3.w;
    }
    float4 sv; sv.x=a0; sv.y=a1; sv.z=a2; sv.w=a3;
    *(float4*)&Sp[(sl*64+n)*4]=sv;
  }
  __syncthreads();
  if(t<256){ int n=t>>2, m=t&3;
    float s=psib[m];
    for(int sl=0;sl<8;sl++) s+=Sp[(sl*64+n)*4+m];
    Sa[n*4+m]=s;
  }
  __syncthreads();
  if(t<64){
    #pragma unroll
    for(int m=0;m<4;m++){
      float v=Sa[t*4+m];
      float mx=wmax64(v);
      float e=expf(v-mx);
      float sm=wsum64(e);
      Sa[t*4+m]=e/sm;
    } }
  __syncthreads();
  { int c=t;
    float a0=0.f,a1=0.f,a2=0.f,a3=0.f;
    for(int n=0;n<64;n++){
      float f=F[n*FS+c];
      float4 am=*(const float4*)&Sa[n*4];
      a0+=am.x*f; a1+=am.y*f; a2+=am.z*f; a3+=am.w*f;
    }
    float* G=ws+OFF_G+(long)w*2048;
    G[c]=a0; G[512+c]=a1; G[1024+c]=a2; G[1536+c]=a3;
  }
}

// ---------------- Z = LN(G @ phi_fold + phib_fold) ----------------
__global__ __launch_bounds__(256) void k_z(const float* __restrict__ nzg, const float* __restrict__ nzb,
                    float* __restrict__ ws){
  __shared__ float Gw[2048];
  __shared__ float red[4];
  int w=blockIdx.x, t=threadIdx.x;
  const float* G=ws+OFF_G+(long)w*2048;
  for(int i4=t;i4<512;i4+=256){ *(float4*)&Gw[i4*4] = *(const float4*)&G[i4*4]; }
  __syncthreads();
  const float* phiT=ws+OFF_PHIT;
  const float* phb=ws+OFF_PHB;
  int c=t;
  float pb=phb[c];
  float a0=pb,a1=pb,a2=pb,a3=pb;
  const float* prow = phiT + (long)c*512;
  for(int k=0;k<512;k+=4){
    float4 pv=*(const float4*)(prow+k);
    float4 g0=*(const float4*)&Gw[k];
    float4 g1=*(const float4*)&Gw[512+k];
    float4 g2=*(const float4*)&Gw[1024+k];
    float4 g3=*(const float4*)&Gw[1536+k];
    a0+=g0.x*pv.x+g0.y*pv.y+g0.z*pv.z+g0.w*pv.w;
    a1+=g1.x*pv.x+g1.y*pv.y+g1.z*pv.z+g1.w*pv.w;
    a2+=g2.x*pv.x+g2.y*pv.y+g2.z*pv.z+g2.w*pv.w;
    a3+=g3.x*pv.x+g3.y*pv.y+g3.z*pv.z+g3.w*pv.w;
  }
  float* Z=ws+OFF_Z+(long)w*1024;
  float g=nzg[c], b=nzb[c];
  float vals[4]={a0,a1,a2,a3};
  #pragma unroll
  for(int m=0;m<4;m++){
    float v=vals[m];
    float s1=blockSum256(v,red,t);
    float s2=blockSum256(v*v,red,t);
    float mm=s1*(1.f/256.f), vv=s2*(1.f/256.f)-mm*mm;
    float rs=rsqrtf(vv+1e-5f);
    Z[m*256+c]=(v-mm)*rs*g+b;
  }
}

// ---------------- attention 1 (summary queries vs window tokens) ----------------
#define FLS 260
__global__ __launch_bounds__(256) void k_attn1(const float* __restrict__ qb, const float* __restrict__ kw,
    const float* __restrict__ kb, const float* __restrict__ vb,
    const float* __restrict__ nzfg, const float* __restrict__ nzfb,
    float* __restrict__ ws){
  __shared__ float Fl[64*FLS];
  __shared__ float Qp[8192];
  __shared__ float Wl[8192];
  __shared__ float Zl[1024];
  __shared__ float QZ[1024];
  __shared__ float Al[2048];
  __shared__ float cbs[32];
  __shared__ float rl[64];
  __shared__ float red[4];
  int w=blockIdx.x, t=threadIdx.x;
  {
    const float* Z=ws+OFF_Z+(long)w*1024;
    for(int i=t;i<1024;i+=256) Zl[i]=Z[i];
  }
  __syncthreads();
  { // QZ[m][o] = Z[m] @ q_w[:,o] + q_b[o]
    const float* qrow=ws+OFF_QT+(long)t*256;
    float b0=qb[t];
    float a0=b0,a1=b0,a2=b0,a3=b0;
    for(int k=0;k<256;k+=4){
      float4 q4=*(const float4*)(qrow+k);
      float4 z0=*(const float4*)&Zl[k];
      float4 z1=*(const float4*)&Zl[256+k];
      float4 z2=*(const float4*)&Zl[512+k];
      float4 z3=*(const float4*)&Zl[768+k];
      a0+=z0.x*q4.x+z0.y*q4.y+z0.z*q4.z+z0.w*q4.w;
      a1+=z1.x*q4.x+z1.y*q4.y+z1.z*q4.z+z1.w*q4.w;
      a2+=z2.x*q4.x+z2.y*q4.y+z2.z*q4.z+z2.w*q4.w;
      a3+=z3.x*q4.x+z3.y*q4.y+z3.z*q4.z+z3.w*q4.w;
    }
    QZ[t]=a0; QZ[256+t]=a1; QZ[512+t]=a2; QZ[768+t]=a3;
  }
  __syncthreads();
  { // Qp[(h,m)][c] = sum_d k_w[c][h*32+d]*QZ[m][h*32+d]
    const float* krow=kw+(long)t*256;
    for(int h=0;h<8;h++){
      float a0=0.f,a1=0.f,a2=0.f,a3=0.f;
      for(int d=0;d<32;d+=4){
        float4 k4=*(const float4*)(krow+h*32+d);
        float4 q0=*(const float4*)&QZ[h*32+d];
        float4 q1=*(const float4*)&QZ[256+h*32+d];
        float4 q2=*(const float4*)&QZ[512+h*32+d];
        float4 q3=*(const float4*)&QZ[768+h*32+d];
        a0+=k4.x*q0.x+k4.y*q0.y+k4.z*q0.z+k4.w*q0.w;
        a1+=k4.x*q1.x+k4.y*q1.y+k4.z*q1.z+k4.w*q1.w;
        a2+=k4.x*q2.x+k4.y*q2.y+k4.z*q2.z+k4.w*q2.w;
        a3+=k4.x*q3.x+k4.y*q3.y+k4.z*q3.z+k4.w*q3.w;
      }
      Qp[(h*4+0)*256+t]=a0; Qp[(h*4+1)*256+t]=a1; Qp[(h*4+2)*256+t]=a2; Qp[(h*4+3)*256+t]=a3;
    }
  }
  if(t<32){ int h=t>>2, m=t&3;
    float a=0.f;
    for(int d=0;d<32;d++) a+=kb[h*32+d]*QZ[m*256+h*32+d];
    cbs[t]=a;
  }
  for(int s=0;s<2;s++){
    __syncthreads();
    const float* Fsrc=ws+(s?OFF_FTW:OFF_FRW)+(long)w*16384;
    const float* rsrc=ws+(s?OFF_RTW:OFF_RRW)+(long)w*64;
    for(int i4=t;i4<4096;i4+=256){
      int n=i4>>6, cq=i4&63;
      float4 v=*(const float4*)(Fsrc+n*256+cq*4);
      float* p=&Fl[n*FLS+cq*4];
      p[0]=v.x; p[1]=v.y; p[2]=v.z; p[3]=v.w;
    }
    if(t<64) rl[t]=rsrc[t];
    __syncthreads();
    { // scores + softmax over n
      int n=t&63, g=t>>6;
      const float* frow=&Fl[n*FLS];
      float acc[8];
      #pragma unroll
      for(int q=0;q<8;q++) acc[q]=cbs[q*4+g];
      for(int k=0;k<256;k+=4){
        float4 f=*(const float4*)(frow+k);
        #pragma unroll
        for(int q=0;q<8;q++){
          float4 p=*(const float4*)&Qp[(q*4+g)*256+k];
          acc[q]+=f.x*p.x+f.y*p.y+f.z*p.z+f.w*p.w;
        }
      }
      float sr=SCALE*rl[n];
      #pragma unroll
      for(int q=0;q<8;q++){
        float a=acc[q]*sr;
        float mx=wmax64(a);
        float e=expf(a-mx);
        float sm=wsum64(e);
        Al[(q*4+g)*64+n]=e/sm;
      }
    }
    __syncthreads();
    { // W[(h,m)][c] = sum_n A * F  (accumulate both sides)
      int c=t;
      float wacc[32];
      #pragma unroll
      for(int P=0;P<32;P++) wacc[P]=0.f;
      for(int n0=0;n0<64;n0+=4){
        float f0=Fl[(n0+0)*FLS+c], f1=Fl[(n0+1)*FLS+c], f2=Fl[(n0+2)*FLS+c], f3=Fl[(n0+3)*FLS+c];
        #pragma unroll
        for(int P=0;P<32;P++){
          float4 a4=*(const float4*)&Al[P*64+n0];
          wacc[P]+=a4.x*f0+a4.y*f1+a4.z*f2+a4.w*f3;
        }
      }
      if(s==0){
        #pragma unroll
        for(int P=0;P<32;P++) Wl[P*256+c]=wacc[P];
      }else{
        #pragma unroll
        for(int P=0;P<32;P++) Wl[P*256+c]+=wacc[P];
      }
    }
  }
  __syncthreads();
  float zh0,zh1,zh2,zh3;
  { // Zh[m][co] = (W_R+W_T)[h(co),m,:] @ v_w[:,co] + 2*v_b[co]
    int co=t, h=co>>5;
    const float* vrow=ws+OFF_VT+(long)co*256;
    float vb2=2.f*vb[co];
    float a0=vb2,a1=vb2,a2=vb2,a3=vb2;
    for(int k=0;k<256;k+=4){
      float4 v4=*(const float4*)(vrow+k);
      float4 w0=*(const float4*)&Wl[(h*4+0)*256+k];
      float4 w1=*(const float4*)&Wl[(h*4+1)*256+k];
      float4 w2=*(const float4*)&Wl[(h*4+2)*256+k];
      float4 w3=*(const float4*)&Wl[(h*4+3)*256+k];
      a0+=w0.x*v4.x+w0.y*v4.y+w0.z*v4.z+w0.w*v4.w;
      a1+=w1.x*v4.x+w1.y*v4.y+w1.z*v4.z+w1.w*v4.w;
      a2+=w2.x*v4.x+w2.y*v4.y+w2.z*v4.z+w2.w*v4.w;
      a3+=w3.x*v4.x+w3.y*v4.y+w3.z*v4.z+w3.w*v4.w;
    }
    zh0=a0; zh1=a1; zh2=a2; zh3=a3;
  }
  { // Zp = LN(Z + ZhR + ZhT)
    int c=t;
    float g=nzfg[c], b=nzfb[c];
    float* Zp=ws+OFF_ZP+(long)w*1024;
    float v4[4]={Zl[c]+zh0, Zl[256+c]+zh1, Zl[512+c]+zh2, Zl[768+c]+zh3};
    #pragma unroll
    for(int m=0;m<4;m++){
      float v=v4[m];
      float s1=blockSum256(v,red,t);
      float s2=blockSum256(v*v,red,t);
      float mm=s1*(1.f/256.f), vv=s2*(1.f/256.f)-mm*mm;
      float rs=rsqrtf(vv+1e-5f);
      Zp[m*256+c]=(v-mm)*rs*g+b;
    }
  }
}

// ---------------- MLP on Zp (8 windows = 32 rows per block) ----------------
__global__ __launch_bounds__(256) void k_mlp(const float* __restrict__ fc1b, const float* __restrict__ fc2w,
                      const float* __restrict__ fc2b, float* __restrict__ ws){
  __shared__ float Zpl[8192];
  __shared__ float Hc[4096];
  int blk=blockIdx.x, t=threadIdx.x;
  long r0=(long)blk*32;
  const float* Zp=ws+OFF_ZP + r0*256;
  for(int i4=t;i4<2048;i4+=256){ *(float4*)&Zpl[i4*4] = *(const float4*)&Zp[i4*4]; }
  float o[32];
  { float b=fc2b[t];
    #pragma unroll
    for(int r=0;r<32;r++) o[r]=b; }
  const float* f1T=ws+OFF_F1T;
  for(int ch=0;ch<8;ch++){
    __syncthreads();
    { int jl=t&127, rg=t>>7;
      int j=ch*128+jl;
      const float* wrow=f1T+(long)j*256;
      float acc[16];
      #pragma unroll
      for(int i=0;i<16;i++) acc[i]=0.f;
      for(int k=0;k<256;k+=4){
        float4 w4=*(const float4*)(wrow+k);
        #pragma unroll
        for(int i=0;i<16;i++){
          float4 z=*(const float4*)&Zpl[(rg*16+i)*256+k];
          acc[i]+=z.x*w4.x+z.y*w4.y+z.z*w4.z+z.w*w4.w;
        }
      }
      float bj=fc1b[j];
      #pragma unroll
      for(int i=0;i<16;i++){
        float x=acc[i]+bj;
        Hc[(rg*16+i)*128+jl]=0.5f*x*(1.f+erff(x*0.70710678118654752f));
      }
    }
    __syncthreads();
    { int c=t;
      const float* f2=fc2w+(long)(ch*128)*256+c;
      for(int j=0;j<128;j++){
        float wv=f2[(long)j*256];
        #pragma unroll
        for(int r=0;r<32;r++) o[r]+=Hc[r*128+j]*wv;
      }
    }
  }
  __syncthreads();
  float* Zp2=ws+OFF_ZP2 + r0*256;
  #pragma unroll
  for(int r=0;r<32;r++) Zp2[(long)r*256+t]=o[r];
}

// ---------------- attention 2 + final LN + window reverse + gamma blend ----------------
__global__ __launch_bounds__(256) void k_final(const float* __restrict__ kbv, const float* __restrict__ qw,
    const float* __restrict__ qbv, const float* __restrict__ vbv,
    const float* __restrict__ nrg, const float* __restrict__ nrb,
    const float* __restrict__ ntg, const float* __restrict__ ntb,
    float* __restrict__ out, float* __restrict__ ws){
  __shared__ float Fl[64*FLS];
  __shared__ float Kp[8192];
  __shared__ float Z2[1024];
  __shared__ float KZ[1024];
  __shared__ float VZ[1024];
  __shared__ float Al[2048];
  __shared__ float cb2[32];
  __shared__ float rl[64];
  int w=blockIdx.x, t=threadIdx.x;
  int b=w>>8, wr=(w>>4)&15, wc=w&15;
  {
    const float* Zp2=ws+OFF_ZP2+(long)w*1024;
    for(int i=t;i<1024;i+=256) Z2[i]=Zp2[i];
  }
  __syncthreads();
  { // KZ, VZ from Zp2
    const float* krow=ws+OFF_KT+(long)t*256;
    const float* vrow=ws+OFF_VT+(long)t*256;
    float kb0=kbv[t], vb0=vbv[t];
    float k0=kb0,k1=kb0,k2=kb0,k3=kb0, v0=vb0,v1=vb0,v2=vb0,v3=vb0;
    for(int k=0;k<256;k+=4){
      float4 kk=*(const float4*)(krow+k);
      float4 vv=*(const float4*)(vrow+k);
      float4 z0=*(const float4*)&Z2[k];
      float4 z1=*(const float4*)&Z2[256+k];
      float4 z2=*(const float4*)&Z2[512+k];
      float4 z3=*(const float4*)&Z2[768+k];
      k0+=z0.x*kk.x+z0.y*kk.y+z0.z*kk.z+z0.w*kk.w;
      k1+=z1.x*kk.x+z1.y*kk.y+z1.z*kk.z+z1.w*kk.w;
      k2+=z2.x*kk.x+z2.y*kk.y+z2.z*kk.z+z2.w*kk.w;
      k3+=z3.x*kk.x+z3.y*kk.y+z3.z*kk.z+z3.w*kk.w;
      v0+=z0.x*vv.x+z0.y*vv.y+z0.z*vv.z+z0.w*vv.w;
      v1+=z1.x*vv.x+z1.y*vv.y+z1.z*vv.z+z1.w*vv.w;
      v2+=z2.x*vv.x+z2.y*vv.y+z2.z*vv.z+z2.w*vv.w;
      v3+=z3.x*vv.x+z3.y*vv.y+z3.z*vv.z+z3.w*vv.w;
    }
    KZ[t]=k0; KZ[256+t]=k1; KZ[512+t]=k2; KZ[768+t]=k3;
    VZ[t]=v0; VZ[256+t]=v1; VZ[512+t]=v2; VZ[768+t]=v3;
  }
  __syncthreads();
  { // Kp[(h,m)][c] = sum_d q_w[c][h*32+d]*KZ[m][h*32+d]
    const float* qrow=qw+(long)t*256;
    for(int h=0;h<8;h++){
      float a0=0.f,a1=0.f,a2=0.f,a3=0.f;
      for(int d=0;d<32;d+=4){
        float4 q4=*(const float4*)(qrow+h*32+d);
        float4 c0=*(const float4*)&KZ[h*32+d];
        float4 c1=*(const float4*)&KZ[256+h*32+d];
        float4 c2=*(const float4*)&KZ[512+h*32+d];
        float4 c3=*(const float4*)&KZ[768+h*32+d];
        a0+=q4.x*c0.x+q4.y*c0.y+q4.z*c0.z+q4.w*c0.w;
        a1+=q4.x*c1.x+q4.y*c1.y+q4.z*c1.z+q4.w*c1.w;
        a2+=q4.x*c2.x+q4.y*c2.y+q4.z*c2.z+q4.w*c2.w;
        a3+=q4.x*c3.x+q4.y*c3.y+q4.z*c3.z+q4.w*c3.w;
      }
      Kp[(h*4+0)*256+t]=a0; Kp[(h*4+1)*256+t]=a1; Kp[(h*4+2)*256+t]=a2; Kp[(h*4+3)*256+t]=a3;
    }
  }
  if(t<32){ int h=t>>2, m=t&3;
    float a=0.f;
    for(int d=0;d<32;d++) a+=qbv[h*32+d]*KZ[m*256+h*32+d];
    cb2[t]=a;
  }
  float gam=ws[OFF_GAM+b];
  float oa[64];
  int lane=t&63, wv=t>>6;
  for(int s=0;s<2;s++){
    __syncthreads();
    const float* Fsrc=ws+(s?OFF_FTW:OFF_FRW)+(long)w*16384;
    const float* rsrc=ws+(s?OFF_RRW:OFF_RTW)+(long)w*64;  // CROSS: R-side attn uses rTw, T-side uses rRw
    for(int i4=t;i4<4096;i4+=256){
      int n=i4>>6, cq=i4&63;
      float4 v=*(const float4*)(Fsrc+n*256+cq*4);
      float* p=&Fl[n*FLS+cq*4];
      p[0]=v.x; p[1]=v.y; p[2]=v.z; p[3]=v.w;
    }
    if(t<64) rl[t]=rsrc[t];
    __syncthreads();
    { // scores over m (4) per (h,n), softmax over m in-thread
      int n=lane;
      const float* frow=&Fl[n*FLS];
      float sr=SCALE*rl[n];
      #pragma unroll
      for(int hh=0;hh<2;hh++){
        int h=wv*2+hh;
        float a0=cb2[h*4+0],a1=cb2[h*4+1],a2=cb2[h*4+2],a3=cb2[h*4+3];
        for(int k=0;k<256;k+=4){
          float4 f=*(const float4*)(frow+k);
          float4 p0=*(const float4*)&Kp[(h*4+0)*256+k];
          float4 p1=*(const float4*)&Kp[(h*4+1)*256+k];
          float4 p2=*(const float4*)&Kp[(h*4+2)*256+k];
          float4 p3=*(const float4*)&Kp[(h*4+3)*256+k];
          a0+=f.x*p0.x+f.y*p0.y+f.z*p0.z+f.w*p0.w;
          a1+=f.x*p1.x+f.y*p1.y+f.z*p1.z+f.w*p1.w;
          a2+=f.x*p2.x+f.y*p2.y+f.z*p2.z+f.w*p2.w;
          a3+=f.x*p3.x+f.y*p3.y+f.z*p3.z+f.w*p3.w;
        }
        a0*=sr; a1*=sr; a2*=sr; a3*=sr;
        float mx=fmaxf(fmaxf(a0,a1),fmaxf(a2,a3));
        float e0=expf(a0-mx),e1=expf(a1-mx),e2=expf(a2-mx),e3=expf(a3-mx);
        float inv=1.f/(e0+e1+e2+e3);
        float4 av; av.x=e0*inv; av.y=e1*inv; av.z=e2*inv; av.w=e3*inv;
        *(float4*)&Al[(h*64+n)*4]=av;
      }
    }
    __syncthreads();
    { // residual + attn-out + LN + gamma blend (wave-local LN: wave handles n=wv+4k, lane owns c=lane+64e)
      float gsc = s? (1.f-gam) : gam;
      float vzr[4][4], gA[4], bA[4];
      #pragma unroll
      for(int e=0;e<4;e++){
        int c=lane+64*e;
        #pragma unroll
        for(int m=0;m<4;m++) vzr[e][m]=VZ[m*256+c];
        gA[e]= s? ntg[c]:nrg[c];
        bA[e]= s? ntb[c]:nrb[c];
      }
      for(int k=0;k<16;k++){
        int n=wv+4*k;
        float val[4]; float s1=0.f,s2=0.f;
        #pragma unroll
        for(int e=0;e<4;e++){
          int c=lane+64*e; int h=c>>5;
          float4 a4=*(const float4*)&Al[(h*64+n)*4];
          float v=Fl[n*FLS+c] + a4.x*vzr[e][0]+a4.y*vzr[e][1]+a4.z*vzr[e][2]+a4.w*vzr[e][3];
          val[e]=v; s1+=v; s2+=v*v;
        }
        s1=wsum64(s1); s2=wsum64(s2);
        float mm=s1*(1.f/256.f), vv2=s2*(1.f/256.f)-mm*mm;
        float rs=rsqrtf(vv2+1e-5f);
        #pragma unroll
        for(int e=0;e<4;e++){
          float lnv=(val[e]-mm)*rs*gA[e]+bA[e];
          if(s==0) oa[k*4+e]=gsc*lnv; else oa[k*4+e]+=gsc*lnv;
        }
      }
    }
  }
  __syncthreads();
  for(int k=0;k<16;k++){
    int n=wv+4*k;
    #pragma unroll
    for(int e=0;e<4;e++){ Fl[n*FLS+lane+64*e]=oa[k*4+e]; }
  }
  __syncthreads();
  { // transposed coalesced-ish output write: 8 contiguous floats per (c,i)
    int c=t;
    long obase=((long)b*256+c)*16384 + (long)wr*1024 + wc*8;
    for(int i=0;i<8;i++){
      float4 v0, v1;
      v0.x=Fl[(i*8+0)*FLS+c]; v0.y=Fl[(i*8+1)*FLS+c]; v0.z=Fl[(i*8+2)*FLS+c]; v0.w=Fl[(i*8+3)*FLS+c];
      v1.x=Fl[(i*8+4)*FLS+c]; v1.y=Fl[(i*8+5)*FLS+c]; v1.z=Fl[(i*8+6)*FLS+c]; v1.w=Fl[(i*8+7)*FLS+c];
      *(float4*)(out+obase+(long)i*128)=v0;
      *(float4*)(out+obase+(long)i*128+4)=v1;
    }
  }
}

extern "C" void kernel_launch(void* const* d_in, const int* in_sizes, int n_in,
                              void* d_out, int out_size, void* d_ws, size_t ws_size,
                              hipStream_t stream){
  (void)in_sizes; (void)n_in; (void)out_size; (void)ws_size;
  const float* F_R=(const float*)d_in[0];
  const float* F_T=(const float*)d_in[1];
  const float* r_R=(const float*)d_in[2];
  const float* r_T=(const float*)d_in[3];
  const float* psi_w=(const float*)d_in[4];
  const float* psi_b=(const float*)d_in[5];
  const float* phi_w=(const float*)d_in[6];
  const float* phi_b=(const float*)d_in[7];
  const float* np_g=(const float*)d_in[8];
  const float* np_b=(const float*)d_in[9];
  const float* nz_g=(const float*)d_in[10];
  const float* nz_b=(const float*)d_in[11];
  const float* q_w=(const float*)d_in[13];
  const float* q_b=(const float*)d_in[14];
  const float* k_w=(const float*)d_in[15];
  const float* k_b=(const float*)d_in[16];
  const float* v_w=(const float*)d_in[17];
  const float* v_b=(const float*)d_in[18];
  const float* nzf_g=(const float*)d_in[19];
  const float* nzf_b=(const float*)d_in[20];
  const float* fc1_w=(const float*)d_in[21];
  const float* fc1_b=(const float*)d_in[22];
  const float* fc2_w=(const float*)d_in[23];
  const float* fc2_b=(const float*)d_in[24];
  const float* nr_g=(const float*)d_in[25];
  const float* nr_b=(const float*)d_in[26];
  const float* nt_g=(const float*)d_in[27];
  const float* nt_b=(const float*)d_in[28];
  const float* g1_w=(const float*)d_in[29];
  const float* g1_b=(const float*)d_in[30];
  const float* g2_w=(const float*)d_in[31];
  const float* g2_b=(const float*)d_in[32];
  float* ws=(float*)d_ws;
  float* out=(float*)d_out;

  hipLaunchKernelGGL(k_prep,  dim3(2305), dim3(256), 0, stream, q_w,k_w,v_w,fc1_w,phi_w,phi_b,ws);
  hipLaunchKernelGGL(k_gamma, dim3(8),    dim3(256), 0, stream, r_R,r_T,g1_w,g1_b,g2_w,g2_b,ws);
  hipLaunchKernelGGL(k_win,   dim3(8,16,8), dim3(256), 0, stream, F_R,F_T,r_R,r_T,ws);
  hipLaunchKernelGGL(k_stage1,dim3(2048), dim3(512), 0, stream, psi_w,psi_b,np_g,np_b,ws);
  hipLaunchKernelGGL(k_z,     dim3(2048), dim3(256), 0, stream, nz_g,nz_b,ws);
  hipLaunchKernelGGL(k_attn1, dim3(2048), dim3(256), 0, stream, q_b,k_w,k_b,v_b,nzf_g,nzf_b,ws);
  hipLaunchKernelGGL(k_mlp,   dim3(256),  dim3(256), 0, stream, fc1_b,fc2_w,fc2_b,ws);
  hipLaunchKernelGGL(k_final, dim3(2048), dim3(256), 0, stream, k_b,q_w,q_b,v_b,nr_g,nr_b,nt_g,nt_b,out,ws);
}

// Round 2
// 2325.875 us; speedup vs baseline: 1.0439x; 1.0439x over previous
//
#include <hip/hip_runtime.h>
#include <math.h>

#define SCALE 0.17677669529663687f

// workspace float offsets
#define OFF_FRW  0l
#define OFF_FTW  33554432l
#define OFF_RRW  67108864l
#define OFF_RTW  67239936l
#define OFF_G    67371008l
#define OFF_Z    71565312l
#define OFF_ZP   73662464l
#define OFF_ZP2  75759616l
#define OFF_QT   77856768l
#define OFF_KT   77922304l
#define OFF_VT   77987840l
#define OFF_F1T  78053376l
#define OFF_PHIT 78315520l
#define OFF_PHB  78446592l
#define OFF_GAM  78446848l

__device__ __forceinline__ float wsum64(float v){
  #pragma unroll
  for(int o=32;o>0;o>>=1) v+=__shfl_xor(v,o,64);
  return v;
}
__device__ __forceinline__ float wmax64(float v){
  #pragma unroll
  for(int o=32;o>0;o>>=1) v=fmaxf(v,__shfl_xor(v,o,64));
  return v;
}
__device__ __forceinline__ float blockSum256(float v, float* red, int t){
  v=wsum64(v);
  __syncthreads();
  if((t&63)==0) red[t>>6]=v;
  __syncthreads();
  return red[0]+red[1]+red[2]+red[3];
}
__device__ __forceinline__ float blockSum512(float v, float* red, int t){
  v=wsum64(v);
  __syncthreads();
  if((t&63)==0) red[t>>6]=v;
  __syncthreads();
  return red[0]+red[1]+red[2]+red[3]+red[4]+red[5]+red[6]+red[7];
}

// swizzled LDS layouts: row of 256 (or 512) floats, float4-column XORed with (n&15)
__device__ __forceinline__ int swz(int n, int c){ return (n<<8) + ((((c>>2)^(n&15))<<2) | (c&3)); }
__device__ __forceinline__ int swz4(int n, int c4){ return (n<<8) + ((c4^(n&15))<<2); }
__device__ __forceinline__ int swz512(int n, int c){ return (n<<9) + ((((c>>2)^(n&15))<<2) | (c&3)); }
__device__ __forceinline__ int swz512_4(int n, int c4){ return (n<<9) + ((c4^(n&15))<<2); }

// ---------------- weight prep: transposes + phi fold ----------------
__global__ __launch_bounds__(256) void k_prep(const float* __restrict__ qw, const float* __restrict__ kw,
                       const float* __restrict__ vw, const float* __restrict__ fc1w,
                       const float* __restrict__ phiw, const float* __restrict__ phibv,
                       float* __restrict__ ws){
  long gid = (long)blockIdx.x*256 + threadIdx.x;
  if(gid < 262144){ long o=gid>>8, i=gid&255; ws[OFF_F1T+gid] = fc1w[i*1024+o]; return; }
  gid -= 262144;
  if(gid < 65536){ long o=gid>>8, i=gid&255; ws[OFF_QT+gid] = qw[i*256+o]; return; }
  gid -= 65536;
  if(gid < 65536){ long o=gid>>8, i=gid&255; ws[OFF_KT+gid] = kw[i*256+o]; return; }
  gid -= 65536;
  if(gid < 65536){ long o=gid>>8, i=gid&255; ws[OFF_VT+gid] = vw[i*256+o]; return; }
  gid -= 65536;
  if(gid < 131072){ long c=gid>>9, k=gid&511; ws[OFF_PHIT+gid] = 0.5f*(phiw[k*512+c] + phiw[k*512+c+256]); return; }
  gid -= 131072;
  if(gid < 256){ ws[OFF_PHB+gid] = 0.5f*(phibv[gid] + phibv[gid+256]); }
}

// ---------------- gamma ----------------
__global__ __launch_bounds__(256) void k_gamma(const float* __restrict__ rR, const float* __restrict__ rT,
                        const float* __restrict__ g1w, const float* __restrict__ g1b,
                        const float* __restrict__ g2w, const float* __restrict__ g2b,
                        float* __restrict__ ws){
  int b=blockIdx.x, t=threadIdx.x;
  const float* pR=rR+(long)b*16384;
  const float* pT=rT+(long)b*16384;
  float sR=0.f, sT=0.f;
  for(int i=t;i<16384;i+=256){ sR+=pR[i]; sT+=pT[i]; }
  __shared__ float red[8];
  sR=wsum64(sR); sT=wsum64(sT);
  if((t&63)==0){ red[t>>6]=sR; red[4+(t>>6)]=sT; }
  __syncthreads();
  if(t==0){
    float mR=(red[0]+red[1]+red[2]+red[3])*(1.f/16384.f);
    float mT=(red[4]+red[5]+red[6]+red[7])*(1.f/16384.f);
    float o=g2b[0];
    for(int j=0;j<8;j++){
      float h=mR*g1w[j]+mT*g1w[8+j]+g1b[j];
      h=fmaxf(h,0.f);
      o+=h*g2w[j];
    }
    ws[OFF_GAM+b]=1.f/(1.f+expf(-o));
  }
}

// ---------------- window partition transpose ----------------
#define TSTRI 129
#define TSTRC 1033
__global__ __launch_bounds__(256) void k_win(const float* __restrict__ FR, const float* __restrict__ FT,
                      const float* __restrict__ rR, const float* __restrict__ rT,
                      float* __restrict__ ws){
  __shared__ float tile[32*TSTRC];
  int cchunk=blockIdx.x, wr=blockIdx.y, b=blockIdx.z, t=threadIdx.x;
  for(int s=0;s<2;s++){
    const float* src = s? FT:FR;
    float* dst = ws + (s? OFF_FTW:OFF_FRW);
    __syncthreads();
    for(int r4=t; r4<8192; r4+=256){
      int row=r4>>5, wq=r4&31;
      int ci=row>>3, i=row&7;
      long saddr = (((long)b*256 + cchunk*32+ci)*128 + wr*8+i)*128 + wq*4;
      float4 v=*(const float4*)(src+saddr);
      float* p=&tile[ci*TSTRC + i*TSTRI + wq*4];
      p[0]=v.x; p[1]=v.y; p[2]=v.z; p[3]=v.w;
    }
    __syncthreads();
    int cl=t&31, tg=t>>5;
    for(int tok=tg; tok<1024; tok+=8){
      int wc=tok>>6, n=tok&63, i=n>>3, j=n&7;
      float v = tile[cl*TSTRC + i*TSTRI + wc*8+j];
      long w = ((long)b*16+wr)*16+wc;
      dst[(w*64+n)*256 + cchunk*32 + cl] = v;
    }
  }
  if(cchunk==0){
    for(int q=0;q<2;q++){
      const float* src=q? rT:rR;
      float* dst=ws + (q? OFF_RTW:OFF_RRW);
      for(int tok=t; tok<1024; tok+=256){
        int wc=tok>>6, n=tok&63, i=n>>3, j=n&7;
        long w=((long)b*16+wr)*16+wc;
        dst[w*64+n] = src[((long)b*128 + wr*8+i)*128 + wc*8+j];
      }
    }
  }
}

// ---------------- stage1: LN(concat) + psi softmax + pooled G ----------------
__global__ __launch_bounds__(512) void k_stage1(const float* __restrict__ psiw, const float* __restrict__ psib,
                         const float* __restrict__ npg, const float* __restrict__ npb,
                         float* __restrict__ ws){
  __shared__ float F[64*512];
  __shared__ float psiT[2048];
  __shared__ float ng[512], nb[512];
  __shared__ float mu[64], rsd[64];
  __shared__ float Sp[2048];
  __shared__ float Sa[256];
  int w=blockIdx.x, t=threadIdx.x;
  const float* FRw = ws+OFF_FRW + (long)w*16384;
  const float* FTw = ws+OFF_FTW + (long)w*16384;
  for(int i4=t;i4<8192;i4+=512){
    int n=i4>>7, cq=i4&127; int c=cq*4;
    float4 v = (c<256)? *(const float4*)(FRw + n*256+c) : *(const float4*)(FTw + n*256+c-256);
    *(float4*)&F[swz512_4(n,cq)] = v;
  }
  ng[t]=npg[t]; nb[t]=npb[t];
  for(int i=t;i<2048;i+=512){ int c=i>>2, m=i&3; psiT[m*512+c]=psiw[i]; }
  __syncthreads();
  { int g=t>>6, l=t&63;
    for(int n=g;n<64;n+=8){
      float s1=0.f,s2=0.f;
      #pragma unroll
      for(int k=0;k<8;k++){ float x=F[swz512(n, l+64*k)]; s1+=x; s2+=x*x; }
      s1=wsum64(s1); s2=wsum64(s2);
      if(l==0){ float mm=s1*(1.f/512.f), vv=s2*(1.f/512.f)-mm*mm; mu[n]=mm; rsd[n]=rsqrtf(vv+1e-5f); }
    } }
  __syncthreads();
  for(int i=t;i<32768;i+=512){ int n=i>>9, c=i&511; int a=swz512(n,c); F[a] = (F[a]-mu[n])*rsd[n]*ng[c]+nb[c]; }
  __syncthreads();
  { int n=t&63, sl=t>>6; int c0=sl*64; int nx=n&15;
    float a0=0.f,a1=0.f,a2=0.f,a3=0.f;
    for(int k=0;k<64;k+=4){
      int c=c0+k; int c4=c>>2;
      float4 f=*(const float4*)&F[swz512_4(n,c4)];
      float4 p0=*(const float4*)&psiT[c];
      float4 p1=*(const float4*)&psiT[512+c];
      float4 p2=*(const float4*)&psiT[1024+c];
      float4 p3=*(const float4*)&psiT[1536+c];
      a0+=f.x*p0.x+f.y*p0.y+f.z*p0.z+f.w*p0.w;
      a1+=f.x*p1.x+f.y*p1.y+f.z*p1.z+f.w*p1.w;
      a2+=f.x*p2.x+f.y*p2.y+f.z*p2.z+f.w*p2.w;
      a3+=f.x*p3.x+f.y*p3.y+f.z*p3.z+f.w*p3.w;
    }
    float4 sv; sv.x=a0; sv.y=a1; sv.z=a2; sv.w=a3;
    *(float4*)&Sp[(sl*64+n)*4]=sv;
    (void)nx;
  }
  __syncthreads();
  if(t<256){ int n=t>>2, m=t&3;
    float s=psib[m];
    for(int sl=0;sl<8;sl++) s+=Sp[(sl*64+n)*4+m];
    Sa[n*4+m]=s;
  }
  __syncthreads();
  if(t<64){
    #pragma unroll
    for(int m=0;m<4;m++){
      float v=Sa[t*4+m];
      float mx=wmax64(v);
      float e=expf(v-mx);
      float sm=wsum64(e);
      Sa[t*4+m]=e/sm;
    } }
  __syncthreads();
  { int c=t;
    float a0=0.f,a1=0.f,a2=0.f,a3=0.f;
    for(int n=0;n<64;n++){
      float f=F[swz512(n,c)];
      float4 am=*(const float4*)&Sa[n*4];
      a0+=am.x*f; a1+=am.y*f; a2+=am.z*f; a3+=am.w*f;
    }
    float* G=ws+OFF_G+(long)w*2048;
    G[c]=a0; G[512+c]=a1; G[1024+c]=a2; G[1536+c]=a3;
  }
}

// ---------------- Z = LN(G @ phi_fold + phib_fold) ----------------
__global__ __launch_bounds__(256) void k_z(const float* __restrict__ nzg, const float* __restrict__ nzb,
                    float* __restrict__ ws){
  __shared__ float Gw[2048];
  __shared__ float red[4];
  int w=blockIdx.x, t=threadIdx.x;
  const float* G=ws+OFF_G+(long)w*2048;
  for(int i4=t;i4<512;i4+=256){ *(float4*)&Gw[i4*4] = *(const float4*)&G[i4*4]; }
  __syncthreads();
  const float* phiT=ws+OFF_PHIT;
  const float* phb=ws+OFF_PHB;
  int c=t;
  float pb=phb[c];
  float a0=pb,a1=pb,a2=pb,a3=pb;
  const float* prow = phiT + (long)c*512;
  for(int k=0;k<512;k+=4){
    float4 pv=*(const float4*)(prow+k);
    float4 g0=*(const float4*)&Gw[k];
    float4 g1=*(const float4*)&Gw[512+k];
    float4 g2=*(const float4*)&Gw[1024+k];
    float4 g3=*(const float4*)&Gw[1536+k];
    a0+=g0.x*pv.x+g0.y*pv.y+g0.z*pv.z+g0.w*pv.w;
    a1+=g1.x*pv.x+g1.y*pv.y+g1.z*pv.z+g1.w*pv.w;
    a2+=g2.x*pv.x+g2.y*pv.y+g2.z*pv.z+g2.w*pv.w;
    a3+=g3.x*pv.x+g3.y*pv.y+g3.z*pv.z+g3.w*pv.w;
  }
  float* Z=ws+OFF_Z+(long)w*1024;
  float g=nzg[c], b=nzb[c];
  float vals[4]={a0,a1,a2,a3};
  #pragma unroll
  for(int m=0;m<4;m++){
    float v=vals[m];
    float s1=blockSum256(v,red,t);
    float s2=blockSum256(v*v,red,t);
    float mm=s1*(1.f/256.f), vv=s2*(1.f/256.f)-mm*mm;
    float rs=rsqrtf(vv+1e-5f);
    Z[m*256+c]=(v-mm)*rs*g+b;
  }
}

// ---------------- attention 1 (summary queries vs window tokens), 512 threads ----------------
__global__ __launch_bounds__(512) void k_attn1(const float* __restrict__ qb, const float* __restrict__ kw,
    const float* __restrict__ kb, const float* __restrict__ vb,
    const float* __restrict__ nzfg, const float* __restrict__ nzfb,
    float* __restrict__ ws){
  __shared__ float Fl[16384];
  __shared__ float Qp[8192];
  __shared__ float Wl[8192];
  __shared__ float Zl[1024];
  __shared__ float QZ[1024];
  __shared__ float Al[2048];
  __shared__ float cbs[32];
  __shared__ float rl[64];
  __shared__ float red[8];
  int w=blockIdx.x, t=threadIdx.x;
  {
    const float* Z=ws+OFF_Z+(long)w*1024;
    for(int i=t;i<1024;i+=512) Zl[i]=Z[i];
  }
  __syncthreads();
  { // QZ partials (split k in halves across t>>8)
    int oo=t&255, half=t>>8; int kb0=half*128;
    const float* qrow=ws+OFF_QT+(long)oo*256+kb0;
    float a0=0.f,a1=0.f,a2=0.f,a3=0.f;
    for(int k=0;k<128;k+=4){
      float4 q4=*(const float4*)(qrow+k);
      float4 z0=*(const float4*)&Zl[kb0+k];
      float4 z1=*(const float4*)&Zl[256+kb0+k];
      float4 z2=*(const float4*)&Zl[512+kb0+k];
      float4 z3=*(const float4*)&Zl[768+kb0+k];
      a0+=z0.x*q4.x+z0.y*q4.y+z0.z*q4.z+z0.w*q4.w;
      a1+=z1.x*q4.x+z1.y*q4.y+z1.z*q4.z+z1.w*q4.w;
      a2+=z2.x*q4.x+z2.y*q4.y+z2.z*q4.z+z2.w*q4.w;
      a3+=z3.x*q4.x+z3.y*q4.y+z3.z*q4.z+z3.w*q4.w;
    }
    int ab=half*1024+oo;
    Al[ab]=a0; Al[ab+256]=a1; Al[ab+512]=a2; Al[ab+768]=a3;
  }
  __syncthreads();
  if(t<256){
    float b0=qb[t];
    QZ[t]      =Al[t]     +Al[1024+t]+b0;
    QZ[256+t]  =Al[256+t] +Al[1280+t]+b0;
    QZ[512+t]  =Al[512+t] +Al[1536+t]+b0;
    QZ[768+t]  =Al[768+t] +Al[1792+t]+b0;
  }
  __syncthreads();
  { // Qp[(h,m)][c]: 4 heads per thread
    int o=t&255, hb=(t>>8)*4;
    const float* krow=kw+(long)o*256;
    for(int hh=0;hh<4;hh++){
      int h=hb+hh;
      float a0=0.f,a1=0.f,a2=0.f,a3=0.f;
      for(int d=0;d<32;d+=4){
        float4 k4=*(const float4*)(krow+h*32+d);
        float4 q0=*(const float4*)&QZ[h*32+d];
        float4 q1=*(const float4*)&QZ[256+h*32+d];
        float4 q2=*(const float4*)&QZ[512+h*32+d];
        float4 q3=*(const float4*)&QZ[768+h*32+d];
        a0+=k4.x*q0.x+k4.y*q0.y+k4.z*q0.z+k4.w*q0.w;
        a1+=k4.x*q1.x+k4.y*q1.y+k4.z*q1.z+k4.w*q1.w;
        a2+=k4.x*q2.x+k4.y*q2.y+k4.z*q2.z+k4.w*q2.w;
        a3+=k4.x*q3.x+k4.y*q3.y+k4.z*q3.z+k4.w*q3.w;
      }
      Qp[(h*4+0)*256+o]=a0; Qp[(h*4+1)*256+o]=a1; Qp[(h*4+2)*256+o]=a2; Qp[(h*4+3)*256+o]=a3;
    }
  }
  if(t<32){ int h=t>>2, m=t&3;
    float a=0.f;
    for(int d=0;d<32;d++) a+=kb[h*32+d]*QZ[m*256+h*32+d];
    cbs[t]=a;
  }
  int pc=t&255, ph=t>>8;          // pooling mapping
  int sn=t&63, sh=t>>6, snx=sn&15; // score mapping
  float wacc[16];
  #pragma unroll
  for(int p=0;p<16;p++) wacc[p]=0.f;
  for(int s=0;s<2;s++){
    __syncthreads();
    const float* Fsrc=ws+(s?OFF_FTW:OFF_FRW)+(long)w*16384;
    const float* rsrc=ws+(s?OFF_RTW:OFF_RRW)+(long)w*64;
    for(int i4=t;i4<4096;i4+=512){
      int n=i4>>6, c4=i4&63;
      *(float4*)&Fl[swz4(n,c4)] = *(const float4*)(Fsrc+n*256+c4*4);
    }
    if(t<64) rl[t]=rsrc[t];
    __syncthreads();
    { // scores: thread (n=sn, h=sh), acc over m
      const float* frow=&Fl[sn<<8];
      float a0=cbs[sh*4+0],a1=cbs[sh*4+1],a2=cbs[sh*4+2],a3=cbs[sh*4+3];
      for(int k4=0;k4<64;k4++){
        float4 f=*(const float4*)(frow+((k4^snx)<<2));
        int k=k4<<2;
        float4 p0=*(const float4*)&Qp[(sh*4+0)*256+k];
        float4 p1=*(const float4*)&Qp[(sh*4+1)*256+k];
        float4 p2=*(const float4*)&Qp[(sh*4+2)*256+k];
        float4 p3=*(const float4*)&Qp[(sh*4+3)*256+k];
        a0+=f.x*p0.x+f.y*p0.y+f.z*p0.z+f.w*p0.w;
        a1+=f.x*p1.x+f.y*p1.y+f.z*p1.z+f.w*p1.w;
        a2+=f.x*p2.x+f.y*p2.y+f.z*p2.z+f.w*p2.w;
        a3+=f.x*p3.x+f.y*p3.y+f.z*p3.z+f.w*p3.w;
      }
      float sr=SCALE*rl[sn];
      float av[4]={a0,a1,a2,a3};
      #pragma unroll
      for(int m=0;m<4;m++){
        float a=av[m]*sr;
        float mx=wmax64(a);
        float e=expf(a-mx);
        float sm=wsum64(e);
        Al[(sh*4+m)*64+sn]=e/sm;
      }
    }
    __syncthreads();
    { // pool: thread (c=pc, P in [ph*16, ph*16+16))
      for(int n0=0;n0<64;n0+=4){
        float f0=Fl[swz(n0+0,pc)];
        float f1=Fl[swz(n0+1,pc)];
        float f2=Fl[swz(n0+2,pc)];
        float f3=Fl[swz(n0+3,pc)];
        #pragma unroll
        for(int p=0;p<16;p++){
          float4 a4=*(const float4*)&Al[(ph*16+p)*64+n0];
          wacc[p]+=a4.x*f0+a4.y*f1+a4.z*f2+a4.w*f3;
        }
      }
    }
  }
  #pragma unroll
  for(int p=0;p<16;p++) Wl[(ph*16+p)*256+pc]=wacc[p];
  __syncthreads();
  { // Zh partials (split k halves)
    int co=t&255, half=t>>8, h=co>>5; int kb0=half*128;
    const float* vrow=ws+OFF_VT+(long)co*256+kb0;
    float a0=0.f,a1=0.f,a2=0.f,a3=0.f;
    for(int k=0;k<128;k+=4){
      float4 v4=*(const float4*)(vrow+k);
      float4 w0=*(const float4*)&Wl[(h*4+0)*256+kb0+k];
      float4 w1=*(const float4*)&Wl[(h*4+1)*256+kb0+k];
      float4 w2=*(const float4*)&Wl[(h*4+2)*256+kb0+k];
      float4 w3=*(const float4*)&Wl[(h*4+3)*256+kb0+k];
      a0+=w0.x*v4.x+w0.y*v4.y+w0.z*v4.z+w0.w*v4.w;
      a1+=w1.x*v4.x+w1.y*v4.y+w1.z*v4.z+w1.w*v4.w;
      a2+=w2.x*v4.x+w2.y*v4.y+w2.z*v4.z+w2.w*v4.w;
      a3+=w3.x*v4.x+w3.y*v4.y+w3.z*v4.z+w3.w*v4.w;
    }
    int ab=half*1024+co;
    Al[ab]=a0; Al[ab+256]=a1; Al[ab+512]=a2; Al[ab+768]=a3;
  }
  __syncthreads();
  { // Zp = LN(Z + ZhR + ZhT)
    float v4a[4]={0.f,0.f,0.f,0.f};
    float g=0.f,bb=0.f;
    if(t<256){
      g=nzfg[t]; bb=nzfb[t];
      float vb2=2.f*vb[t];
      #pragma unroll
      for(int m=0;m<4;m++) v4a[m]=Zl[m*256+t]+Al[m*256+t]+Al[1024+m*256+t]+vb2;
    }
    float* Zp=ws+OFF_ZP+(long)w*1024;
    #pragma unroll
    for(int m=0;m<4;m++){
      float v=v4a[m];
      float s1=blockSum512(v,red,t);
      float s2=blockSum512(v*v,red,t);
      if(t<256){
        float mm=s1*(1.f/256.f), vv=s2*(1.f/256.f)-mm*mm;
        float rs=rsqrtf(vv+1e-5f);
        Zp[m*256+t]=(v-mm)*rs*g+bb;
      }
    }
  }
}

// ---------------- MLP on Zp (16 rows per block, 512 blocks) ----------------
__global__ __launch_bounds__(256) void k_mlp(const float* __restrict__ fc1b, const float* __restrict__ fc2w,
                      const float* __restrict__ fc2b, float* __restrict__ ws){
  __shared__ float Zpl[4096];
  __shared__ float Hc[2048];
  int blk=blockIdx.x, t=threadIdx.x;
  long r0=(long)blk*16;
  const float* Zp=ws+OFF_ZP + r0*256;
  for(int i4=t;i4<1024;i4+=256){ *(float4*)&Zpl[i4*4] = *(const float4*)&Zp[i4*4]; }
  float o[16];
  { float b=fc2b[t];
    #pragma unroll
    for(int r=0;r<16;r++) o[r]=b; }
  const float* f1T=ws+OFF_F1T;
  for(int ch=0;ch<8;ch++){
    __syncthreads();
    { int jl=t&127, rg=t>>7;
      int j=ch*128+jl;
      const float* wrow=f1T+(long)j*256;
      float acc[8];
      #pragma unroll
      for(int i=0;i<8;i++) acc[i]=0.f;
      for(int k=0;k<256;k+=4){
        float4 w4=*(const float4*)(wrow+k);
        #pragma unroll
        for(int i=0;i<8;i++){
          float4 z=*(const float4*)&Zpl[(rg*8+i)*256+k];
          acc[i]+=z.x*w4.x+z.y*w4.y+z.z*w4.z+z.w*w4.w;
        }
      }
      float bj=fc1b[j];
      #pragma unroll
      for(int i=0;i<8;i++){
        float x=acc[i]+bj;
        Hc[(rg*8+i)*128+jl]=0.5f*x*(1.f+erff(x*0.70710678118654752f));
      }
    }
    __syncthreads();
    { int c=t;
      const float* f2=fc2w+(long)(ch*128)*256+c;
      for(int j=0;j<128;j++){
        float wv=f2[(long)j*256];
        #pragma unroll
        for(int r=0;r<16;r++) o[r]+=Hc[r*128+j]*wv;
      }
    }
  }
  float* Zp2=ws+OFF_ZP2 + r0*256;
  #pragma unroll
  for(int r=0;r<16;r++) Zp2[(long)r*256+t]=o[r];
}

// ---------------- attention 2 + final LN + window reverse + gamma blend, 512 threads ----------------
__global__ __launch_bounds__(512) void k_final(const float* __restrict__ kbv, const float* __restrict__ qw,
    const float* __restrict__ qbv, const float* __restrict__ vbv,
    const float* __restrict__ nrg, const float* __restrict__ nrb,
    const float* __restrict__ ntg, const float* __restrict__ ntb,
    float* __restrict__ out, float* __restrict__ ws){
  __shared__ float Fl[16384];
  __shared__ float Kp[8192];
  __shared__ float Z2[1024];
  __shared__ float KZ[1024];
  __shared__ float VZ[1024];
  __shared__ float Al[2048];
  __shared__ float cb2[32];
  __shared__ float rl[64];
  int w=blockIdx.x, t=threadIdx.x;
  int b=w>>8, wr=(w>>4)&15, wc=w&15;
  {
    const float* Zp2=ws+OFF_ZP2+(long)w*1024;
    for(int i=t;i<1024;i+=512) Z2[i]=Zp2[i];
  }
  __syncthreads();
  { // KZ/VZ partials into Kp scratch
    int oo=t&255, half=t>>8; int kb0=half*128;
    const float* krow=ws+OFF_KT+(long)oo*256+kb0;
    const float* vrow=ws+OFF_VT+(long)oo*256+kb0;
    float k0=0.f,k1=0.f,k2=0.f,k3=0.f, v0=0.f,v1=0.f,v2=0.f,v3=0.f;
    for(int k=0;k<128;k+=4){
      float4 kk=*(const float4*)(krow+k);
      float4 vv=*(const float4*)(vrow+k);
      float4 z0=*(const float4*)&Z2[kb0+k];
      float4 z1=*(const float4*)&Z2[256+kb0+k];
      float4 z2=*(const float4*)&Z2[512+kb0+k];
      float4 z3=*(const float4*)&Z2[768+kb0+k];
      k0+=z0.x*kk.x+z0.y*kk.y+z0.z*kk.z+z0.w*kk.w;
      k1+=z1.x*kk.x+z1.y*kk.y+z1.z*kk.z+z1.w*kk.w;
      k2+=z2.x*kk.x+z2.y*kk.y+z2.z*kk.z+z2.w*kk.w;
      k3+=z3.x*kk.x+z3.y*kk.y+z3.z*kk.z+z3.w*kk.w;
      v0+=z0.x*vv.x+z0.y*vv.y+z0.z*vv.z+z0.w*vv.w;
      v1+=z1.x*vv.x+z1.y*vv.y+z1.z*vv.z+z1.w*vv.w;
      v2+=z2.x*vv.x+z2.y*vv.y+z2.z*vv.z+z2.w*vv.w;
      v3+=z3.x*vv.x+z3.y*vv.y+z3.z*vv.z+z3.w*vv.w;
    }
    int ab=half*1024+oo;
    Kp[ab]=k0; Kp[ab+256]=k1; Kp[ab+512]=k2; Kp[ab+768]=k3;
    Kp[4096+ab]=v0; Kp[4096+ab+256]=v1; Kp[4096+ab+512]=v2; Kp[4096+ab+768]=v3;
  }
  __syncthreads();
  if(t<256){
    float kb0=kbv[t], vb0=vbv[t];
    #pragma unroll
    for(int m=0;m<4;m++){
      KZ[m*256+t]=Kp[m*256+t]+Kp[1024+m*256+t]+kb0;
      VZ[m*256+t]=Kp[4096+m*256+t]+Kp[5120+m*256+t]+vb0;
    }
  }
  __syncthreads();
  { // Kp[(h,m)][c]: 4 heads per thread
    int o=t&255, hb=(t>>8)*4;
    const float* qrow=qw+(long)o*256;
    for(int hh=0;hh<4;hh++){
      int h=hb+hh;
      float a0=0.f,a1=0.f,a2=0.f,a3=0.f;
      for(int d=0;d<32;d+=4){
        float4 q4=*(const float4*)(qrow+h*32+d);
        float4 c0=*(const float4*)&KZ[h*32+d];
        float4 c1=*(const float4*)&KZ[256+h*32+d];
        float4 c2=*(const float4*)&KZ[512+h*32+d];
        float4 c3=*(const float4*)&KZ[768+h*32+d];
        a0+=q4.x*c0.x+q4.y*c0.y+q4.z*c0.z+q4.w*c0.w;
        a1+=q4.x*c1.x+q4.y*c1.y+q4.z*c1.z+q4.w*c1.w;
        a2+=q4.x*c2.x+q4.y*c2.y+q4.z*c2.z+q4.w*c2.w;
        a3+=q4.x*c3.x+q4.y*c3.y+q4.z*c3.z+q4.w*c3.w;
      }
      Kp[(h*4+0)*256+o]=a0; Kp[(h*4+1)*256+o]=a1; Kp[(h*4+2)*256+o]=a2; Kp[(h*4+3)*256+o]=a3;
    }
  }
  if(t<32){ int h=t>>2, m=t&3;
    float a=0.f;
    for(int d=0;d<32;d++) a+=qbv[h*32+d]*KZ[m*256+h*32+d];
    cb2[t]=a;
  }
  float gam=ws[OFF_GAM+b];
  float oa[32];
  int lane=t&63, wv=t>>6, snx=lane&15;
  for(int s=0;s<2;s++){
    __syncthreads();
    const float* Fsrc=ws+(s?OFF_FTW:OFF_FRW)+(long)w*16384;
    const float* rsrc=ws+(s?OFF_RRW:OFF_RTW)+(long)w*64;  // CROSS: R-side attn uses rTw, T-side uses rRw
    for(int i4=t;i4<4096;i4+=512){
      int n=i4>>6, c4=i4&63;
      *(float4*)&Fl[swz4(n,c4)] = *(const float4*)(Fsrc+n*256+c4*4);
    }
    if(t<64) rl[t]=rsrc[t];
    __syncthreads();
    { // scores: thread (n=lane, h=wv); softmax over m in-thread
      const float* frow=&Fl[lane<<8];
      int h=wv;
      float a0=cb2[h*4+0],a1=cb2[h*4+1],a2=cb2[h*4+2],a3=cb2[h*4+3];
      for(int k4=0;k4<64;k4++){
        float4 f=*(const float4*)(frow+((k4^snx)<<2));
        int k=k4<<2;
        float4 p0=*(const float4*)&Kp[(h*4+0)*256+k];
        float4 p1=*(const float4*)&Kp[(h*4+1)*256+k];
        float4 p2=*(const float4*)&Kp[(h*4+2)*256+k];
        float4 p3=*(const float4*)&Kp[(h*4+3)*256+k];
        a0+=f.x*p0.x+f.y*p0.y+f.z*p0.z+f.w*p0.w;
        a1+=f.x*p1.x+f.y*p1.y+f.z*p1.z+f.w*p1.w;
        a2+=f.x*p2.x+f.y*p2.y+f.z*p2.z+f.w*p2.w;
        a3+=f.x*p3.x+f.y*p3.y+f.z*p3.z+f.w*p3.w;
      }
      float sr=SCALE*rl[lane];
      a0*=sr; a1*=sr; a2*=sr; a3*=sr;
      float mx=fmaxf(fmaxf(a0,a1),fmaxf(a2,a3));
      float e0=expf(a0-mx),e1=expf(a1-mx),e2=expf(a2-mx),e3=expf(a3-mx);
      float inv=1.f/(e0+e1+e2+e3);
      float4 av; av.x=e0*inv; av.y=e1*inv; av.z=e2*inv; av.w=e3*inv;
      *(float4*)&Al[(h*64+lane)*4]=av;
    }
    __syncthreads();
    { // residual + attn-out + LN + gamma blend; wave wv handles n=wv+8k
      float gsc = s? (1.f-gam) : gam;
      float vzr[4][4], gA[4], bA[4];
      #pragma unroll
      for(int e=0;e<4;e++){
        int c=lane+64*e;
        #pragma unroll
        for(int m=0;m<4;m++) vzr[e][m]=VZ[m*256+c];
        gA[e]= s? ntg[c]:nrg[c];
        bA[e]= s? ntb[c]:nrb[c];
      }
      for(int k=0;k<8;k++){
        int n=wv+8*k;
        float val[4]; float s1=0.f,s2=0.f;
        #pragma unroll
        for(int e=0;e<4;e++){
          int c=lane+64*e; int h2=c>>5;
          float4 a4=*(const float4*)&Al[(h2*64+n)*4];
          float v=Fl[swz(n,c)] + a4.x*vzr[e][0]+a4.y*vzr[e][1]+a4.z*vzr[e][2]+a4.w*vzr[e][3];
          val[e]=v; s1+=v; s2+=v*v;
        }
        s1=wsum64(s1); s2=wsum64(s2);
        float mm=s1*(1.f/256.f), vv2=s2*(1.f/256.f)-mm*mm;
        float rs=rsqrtf(vv2+1e-5f);
        #pragma unroll
        for(int e=0;e<4;e++){
          float lnv=(val[e]-mm)*rs*gA[e]+bA[e];
          if(s==0) oa[k*4+e]=gsc*lnv; else oa[k*4+e]+=gsc*lnv;
        }
      }
    }
  }
  __syncthreads();
  for(int k=0;k<8;k++){
    int n=wv+8*k;
    #pragma unroll
    for(int e=0;e<4;e++){ Fl[swz(n,lane+64*e)]=oa[k*4+e]; }
  }
  __syncthreads();
  { // transposed output write: 8 contiguous floats per (c,i); i split across t>>8
    int c=t&255, ih=t>>8;
    long obase=((long)b*256+c)*16384 + (long)wr*1024 + wc*8;
    for(int ii=0;ii<4;ii++){
      int i=ih*4+ii;
      float4 v0, v1;
      v0.x=Fl[swz(i*8+0,c)]; v0.y=Fl[swz(i*8+1,c)]; v0.z=Fl[swz(i*8+2,c)]; v0.w=Fl[swz(i*8+3,c)];
      v1.x=Fl[swz(i*8+4,c)]; v1.y=Fl[swz(i*8+5,c)]; v1.z=Fl[swz(i*8+6,c)]; v1.w=Fl[swz(i*8+7,c)];
      *(float4*)(out+obase+(long)i*128)=v0;
      *(float4*)(out+obase+(long)i*128+4)=v1;
    }
  }
}

extern "C" void kernel_launch(void* const* d_in, const int* in_sizes, int n_in,
                              void* d_out, int out_size, void* d_ws, size_t ws_size,
                              hipStream_t stream){
  (void)in_sizes; (void)n_in; (void)out_size; (void)ws_size;
  const float* F_R=(const float*)d_in[0];
  const float* F_T=(const float*)d_in[1];
  const float* r_R=(const float*)d_in[2];
  const float* r_T=(const float*)d_in[3];
  const float* psi_w=(const float*)d_in[4];
  const float* psi_b=(const float*)d_in[5];
  const float* phi_w=(const float*)d_in[6];
  const float* phi_b=(const float*)d_in[7];
  const float* np_g=(const float*)d_in[8];
  const float* np_b=(const float*)d_in[9];
  const float* nz_g=(const float*)d_in[10];
  const float* nz_b=(const float*)d_in[11];
  const float* q_w=(const float*)d_in[13];
  const float* q_b=(const float*)d_in[14];
  const float* k_w=(const float*)d_in[15];
  const float* k_b=(const float*)d_in[16];
  const float* v_w=(const float*)d_in[17];
  const float* v_b=(const float*)d_in[18];
  const float* nzf_g=(const float*)d_in[19];
  const float* nzf_b=(const float*)d_in[20];
  const float* fc1_w=(const float*)d_in[21];
  const float* fc1_b=(const float*)d_in[22];
  const float* fc2_w=(const float*)d_in[23];
  const float* fc2_b=(const float*)d_in[24];
  const float* nr_g=(const float*)d_in[25];
  const float* nr_b=(const float*)d_in[26];
  const float* nt_g=(const float*)d_in[27];
  const float* nt_b=(const float*)d_in[28];
  const float* g1_w=(const float*)d_in[29];
  const float* g1_b=(const float*)d_in[30];
  const float* g2_w=(const float*)d_in[31];
  const float* g2_b=(const float*)d_in[32];
  float* ws=(float*)d_ws;
  float* out=(float*)d_out;

  hipLaunchKernelGGL(k_prep,  dim3(2305), dim3(256), 0, stream, q_w,k_w,v_w,fc1_w,phi_w,phi_b,ws);
  hipLaunchKernelGGL(k_gamma, dim3(8),    dim3(256), 0, stream, r_R,r_T,g1_w,g1_b,g2_w,g2_b,ws);
  hipLaunchKernelGGL(k_win,   dim3(8,16,8), dim3(256), 0, stream, F_R,F_T,r_R,r_T,ws);
  hipLaunchKernelGGL(k_stage1,dim3(2048), dim3(512), 0, stream, psi_w,psi_b,np_g,np_b,ws);
  hipLaunchKernelGGL(k_z,     dim3(2048), dim3(256), 0, stream, nz_g,nz_b,ws);
  hipLaunchKernelGGL(k_attn1, dim3(2048), dim3(512), 0, stream, q_b,k_w,k_b,v_b,nzf_g,nzf_b,ws);
  hipLaunchKernelGGL(k_mlp,   dim3(512),  dim3(256), 0, stream, fc1_b,fc2_w,fc2_b,ws);
  hipLaunchKernelGGL(k_final, dim3(2048), dim3(512), 0, stream, k_b,q_w,q_b,v_b,nr_g,nr_b,nt_g,nt_b,out,ws);
}